// Round 2
// baseline (598.434 us; speedup 1.0000x reference)
//
#include <hip/hip_runtime.h>

// SingleVQC: B=32768 batch elements, 8 qubits (DIM=256), 4 VQC blocks,
// each = RY(0.5*x) layer + 4 depth layers (Rot gates + CNOT ring) + Z-expvals.
// Layout: one wave (64 lanes) per batch element; 4 complex amplitudes per lane.
// Amplitude index i = lane*4 + r  -> bits 0..1 = r (in-register), bits 2..7 = lane.
// Qubit q acts on amplitude bit b = 7 - q (from the reference's reshape).

#define DI __device__ __forceinline__

// ---------------- gate-table prologue -------------------------------------
// theta: (4 vqc, 4 depth, 8 qubits, 3) fp32.  Output: 128 gates x 8 floats
// (g00.re, g00.im, g01.re, g01.im, g10.re, g10.im, g11.re, g11.im)
__global__ void gate_table_k(const float* __restrict__ theta,
                             float* __restrict__ gt) {
    int idx = blockIdx.x * blockDim.x + threadIdx.x;
    if (idx >= 128) return;
    float phi = theta[idx * 3 + 0];
    float th  = theta[idx * 3 + 1];
    float om  = theta[idx * 3 + 2];
    float ct = __cosf(0.5f * th),         st = __sinf(0.5f * th);
    float ca = __cosf(0.5f * (phi - om)), sa = __sinf(0.5f * (phi - om));
    float cb = __cosf(0.5f * (phi + om)), sb = __sinf(0.5f * (phi + om));
    // g00 = e^{-i(phi+om)/2} ct ; g01 = -e^{+i(phi-om)/2} st
    // g10 = e^{-i(phi-om)/2} st ; g11 = e^{+i(phi+om)/2} ct
    float* g = gt + idx * 8;
    g[0] =  cb * ct;  g[1] = -sb * ct;
    g[2] = -ca * st;  g[3] = -sa * st;
    g[4] =  ca * st;  g[5] = -sa * st;
    g[6] =  cb * ct;  g[7] =  sb * ct;
}

// ---------------- main sim ------------------------------------------------
__global__ __launch_bounds__(256) void vqc_k(const float* __restrict__ x,
                                             const float* __restrict__ gt,
                                             float* __restrict__ out) {
    const int lane  = threadIdx.x & 63;
    const int wid   = threadIdx.x >> 6;
    const int batch = blockIdx.x * 4 + wid;

    float xcur[8];
#pragma unroll
    for (int q = 0; q < 8; ++q) xcur[q] = x[batch * 8 + q];

    float ar[4], ai[4];
    float ex[8];

    for (int v = 0; v < 4; ++v) {   // 4 VQC blocks (runtime loop, same body)
        // ---- RY layer applied to |0..0> == real tensor product ----
        float cq[8], sq[8];
#pragma unroll
        for (int q = 0; q < 8; ++q) {
            float h = 0.5f * xcur[q];
            sq[q] = __sinf(h);
            cq[q] = __cosf(h);
        }
        // bits 2..7 come from the lane id (bit b <-> qubit 7-b)
        float prodL = 1.0f;
#pragma unroll
        for (int b = 2; b < 8; ++b) {
            const int q = 7 - b;
            prodL *= ((lane >> (b - 2)) & 1) ? sq[q] : cq[q];
        }
        ar[0] = prodL * cq[6] * cq[7]; ai[0] = 0.0f;
        ar[1] = prodL * cq[6] * sq[7]; ai[1] = 0.0f;
        ar[2] = prodL * sq[6] * cq[7]; ai[2] = 0.0f;
        ar[3] = prodL * sq[6] * sq[7]; ai[3] = 0.0f;

        // ---- depth layers ----
#pragma unroll
        for (int l = 0; l < 4; ++l) {
            const float* gl = gt + ((v * 4 + l) * 8) * 8;
            // 8 Rot gates
#pragma unroll
            for (int q = 0; q < 8; ++q) {
                const float* g = gl + q * 8;
                const float g00r = g[0], g00i = g[1], g01r = g[2], g01i = g[3];
                const float g10r = g[4], g10i = g[5], g11r = g[6], g11i = g[7];
                const int b = 7 - q;
                if (b >= 2) {                       // cross-lane pairing
                    const int xm    = 1 << (b - 2);
                    const int mybit = (lane >> (b - 2)) & 1;
                    const float cAr = mybit ? g11r : g00r;   // coeff on local amp
                    const float cAi = mybit ? g11i : g00i;
                    const float cBr = mybit ? g10r : g01r;   // coeff on partner amp
                    const float cBi = mybit ? g10i : g01i;
#pragma unroll
                    for (int r = 0; r < 4; ++r) {
                        const float oR = __shfl_xor(ar[r], xm, 64);
                        const float oI = __shfl_xor(ai[r], xm, 64);
                        const float nR = cAr * ar[r] - cAi * ai[r] + cBr * oR - cBi * oI;
                        const float nI = cAr * ai[r] + cAi * ar[r] + cBr * oI + cBi * oR;
                        ar[r] = nR; ai[r] = nI;
                    }
                } else {                            // in-register pairing
                    const int step = 1 << b;
#pragma unroll
                    for (int r0 = 0; r0 < 4; ++r0) {
                        if ((r0 & step) == 0) {
                            const int r1 = r0 | step;
                            const float a0r = ar[r0], a0i = ai[r0];
                            const float a1r = ar[r1], a1i = ai[r1];
                            ar[r0] = g00r * a0r - g00i * a0i + g01r * a1r - g01i * a1i;
                            ai[r0] = g00r * a0i + g00i * a0r + g01r * a1i + g01i * a1r;
                            ar[r1] = g10r * a0r - g10i * a0i + g11r * a1r - g11i * a1i;
                            ai[r1] = g10r * a0i + g10i * a0r + g11r * a1i + g11i * a1r;
                        }
                    }
                }
            }
            // CNOT ring: control q -> target (q + (l+1)) % 8   (depth=4 so l%7+1 == l+1)
            const int roff = l + 1;
#pragma unroll
            for (int q = 0; q < 8; ++q) {
                const int t  = (q + roff) & 7;
                const int bc = 7 - q;      // control amplitude bit
                const int bt = 7 - t;      // target amplitude bit
                if (bt >= 2) {             // target is a lane bit
                    const int xm = 1 << (bt - 2);
                    if (bc >= 2) {         // control is a lane bit
                        const int cbit = (lane >> (bc - 2)) & 1;
#pragma unroll
                        for (int r = 0; r < 4; ++r) {
                            const float oR = __shfl_xor(ar[r], xm, 64);
                            const float oI = __shfl_xor(ai[r], xm, 64);
                            ar[r] = cbit ? oR : ar[r];
                            ai[r] = cbit ? oI : ai[r];
                        }
                    } else {               // control is a register bit
#pragma unroll
                        for (int r = 0; r < 4; ++r) {
                            if ((r >> bc) & 1) {
                                ar[r] = __shfl_xor(ar[r], xm, 64);
                                ai[r] = __shfl_xor(ai[r], xm, 64);
                            }
                        }
                    }
                } else {                   // target is a register bit
                    const int step = 1 << bt;
                    if (bc >= 2) {         // control lane bit: predicated reg swap
                        const int cbit = (lane >> (bc - 2)) & 1;
#pragma unroll
                        for (int r0 = 0; r0 < 4; ++r0) {
                            if (((r0 >> bt) & 1) == 0) {
                                const int r1 = r0 | step;
                                const float t0r = cbit ? ar[r1] : ar[r0];
                                const float t0i = cbit ? ai[r1] : ai[r0];
                                const float t1r = cbit ? ar[r0] : ar[r1];
                                const float t1i = cbit ? ai[r0] : ai[r1];
                                ar[r0] = t0r; ai[r0] = t0i;
                                ar[r1] = t1r; ai[r1] = t1i;
                            }
                        }
                    } else {               // both in-register: static permutation
#pragma unroll
                        for (int r0 = 0; r0 < 4; ++r0) {
                            if (((r0 >> bc) & 1) == 1 && ((r0 >> bt) & 1) == 0) {
                                const int r1 = r0 | step;
                                float tr = ar[r0]; ar[r0] = ar[r1]; ar[r1] = tr;
                                float ti = ai[r0]; ai[r0] = ai[r1]; ai[r1] = ti;
                            }
                        }
                    }
                }
            }
        }

        // ---- Z expvals ----
        const float p0 = ar[0] * ar[0] + ai[0] * ai[0];
        const float p1 = ar[1] * ar[1] + ai[1] * ai[1];
        const float p2 = ar[2] * ar[2] + ai[2] * ai[2];
        const float p3 = ar[3] * ar[3] + ai[3] * ai[3];
        const float psum = (p0 + p1) + (p2 + p3);
#pragma unroll
        for (int q = 0; q < 8; ++q) {
            const int b = 7 - q;
            float vq;
            if (b == 0)      vq = (p0 - p1) + (p2 - p3);
            else if (b == 1) vq = (p0 + p1) - (p2 + p3);
            else             vq = ((lane >> (b - 2)) & 1) ? -psum : psum;
#pragma unroll
            for (int m = 1; m < 64; m <<= 1)
                vq += __shfl_xor(vq, m, 64);
            ex[q] = vq;
        }
#pragma unroll
        for (int q = 0; q < 8; ++q) xcur[q] = ex[q];
    }

    // output = H[:, 4] * (float32)(pi - eps_f32)
    const float MULT = (float)(3.141592653589793 - 1.1920928955078125e-07);
    if (lane == 0) out[batch] = ex[4] * MULT;
}

// ---------------- launcher ------------------------------------------------
extern "C" void kernel_launch(void* const* d_in, const int* in_sizes, int n_in,
                              void* d_out, int out_size, void* d_ws, size_t ws_size,
                              hipStream_t stream) {
    const float* x     = (const float*)d_in[0];   // (32768, 8) fp32
    const float* theta = (const float*)d_in[1];   // (4, 4, 8, 3) fp32
    float* out = (float*)d_out;                   // (32768,) fp32
    float* gt  = (float*)d_ws;                    // 128 gates * 8 floats = 4 KB

    gate_table_k<<<1, 128, 0, stream>>>(theta, gt);

    const int B = 32768;
    const int waves_per_block = 4;                 // 256 threads
    vqc_k<<<B / waves_per_block, 256, 0, stream>>>(x, gt, out);
}

// Round 3
// 205.589 us; speedup vs baseline: 2.9108x; 2.9108x over previous
//
#include <hip/hip_runtime.h>

// SingleVQC via MFMA: each VQC block = RY(x) state build (real tensor product)
// followed by a FIXED 256x256 complex unitary U_v (depends only on theta) and
// Z-expvals. U_v is prebuilt (bf16) by simulating 256 basis columns with the
// verified shuffle-sim machinery; the main kernel does fused
// s-build -> bf16 GEMM (re,im) -> |Y|^2 -> signed reductions -> sin/cos, x4 VQCs.
//
// Amplitude bit convention (from reference reshape): qubit q <-> amp bit 7-q.

typedef __attribute__((ext_vector_type(8))) short  bf16x8;
typedef __attribute__((ext_vector_type(4))) float  f32x4;

__device__ __forceinline__ ushort f2bf(float f) {
    unsigned u = __builtin_bit_cast(unsigned, f);
    u += 0x7fffu + ((u >> 16) & 1u);          // RNE
    return (ushort)(u >> 16);
}
__device__ __forceinline__ unsigned pack2(float a, float b) {
    return ((unsigned)f2bf(b) << 16) | (unsigned)f2bf(a);
}

// ---------------- gate-table prologue (unchanged, verified) ---------------
__global__ void gate_table_k(const float* __restrict__ theta,
                             float* __restrict__ gt) {
    int idx = blockIdx.x * blockDim.x + threadIdx.x;
    if (idx >= 128) return;
    float phi = theta[idx * 3 + 0];
    float th  = theta[idx * 3 + 1];
    float om  = theta[idx * 3 + 2];
    float ct = __cosf(0.5f * th),         st = __sinf(0.5f * th);
    float ca = __cosf(0.5f * (phi - om)), sa = __sinf(0.5f * (phi - om));
    float cb = __cosf(0.5f * (phi + om)), sb = __sinf(0.5f * (phi + om));
    float* g = gt + idx * 8;
    g[0] =  cb * ct;  g[1] = -sb * ct;
    g[2] = -ca * st;  g[3] = -sa * st;
    g[4] =  ca * st;  g[5] = -sa * st;
    g[6] =  cb * ct;  g[7] =  sb * ct;
}

// ---------------- U-build: one wave per (vqc, basis column) ---------------
// Exactly the round-2 verified depth-layer code, init = e_j, no RY/expvals.
__global__ void ubuild_k(const float* __restrict__ gt,
                         ushort* __restrict__ Ure, ushort* __restrict__ Uim) {
    const int lane = threadIdx.x & 63;
    const int wid  = threadIdx.x >> 6;
    const int wg   = blockIdx.x * 4 + wid;     // 0..1023
    const int v    = wg >> 8;                  // 0..3
    const int j    = wg & 255;                 // basis column

    float ar[4], ai[4];
#pragma unroll
    for (int r = 0; r < 4; ++r) {
        ar[r] = ((lane * 4 + r) == j) ? 1.0f : 0.0f;
        ai[r] = 0.0f;
    }

#pragma unroll
    for (int l = 0; l < 4; ++l) {
        const float* gl = gt + ((v * 4 + l) * 8) * 8;
#pragma unroll
        for (int q = 0; q < 8; ++q) {
            const float* g = gl + q * 8;
            const float g00r = g[0], g00i = g[1], g01r = g[2], g01i = g[3];
            const float g10r = g[4], g10i = g[5], g11r = g[6], g11i = g[7];
            const int b = 7 - q;
            if (b >= 2) {
                const int xm    = 1 << (b - 2);
                const int mybit = (lane >> (b - 2)) & 1;
                const float cAr = mybit ? g11r : g00r;
                const float cAi = mybit ? g11i : g00i;
                const float cBr = mybit ? g10r : g01r;
                const float cBi = mybit ? g10i : g01i;
#pragma unroll
                for (int r = 0; r < 4; ++r) {
                    const float oR = __shfl_xor(ar[r], xm, 64);
                    const float oI = __shfl_xor(ai[r], xm, 64);
                    const float nR = cAr * ar[r] - cAi * ai[r] + cBr * oR - cBi * oI;
                    const float nI = cAr * ai[r] + cAi * ar[r] + cBr * oI + cBi * oR;
                    ar[r] = nR; ai[r] = nI;
                }
            } else {
                const int step = 1 << b;
#pragma unroll
                for (int r0 = 0; r0 < 4; ++r0) {
                    if ((r0 & step) == 0) {
                        const int r1 = r0 | step;
                        const float a0r = ar[r0], a0i = ai[r0];
                        const float a1r = ar[r1], a1i = ai[r1];
                        ar[r0] = g00r * a0r - g00i * a0i + g01r * a1r - g01i * a1i;
                        ai[r0] = g00r * a0i + g00i * a0r + g01r * a1i + g01i * a1r;
                        ar[r1] = g10r * a0r - g10i * a0i + g11r * a1r - g11i * a1i;
                        ai[r1] = g10r * a0i + g10i * a0r + g11r * a1i + g11i * a1r;
                    }
                }
            }
        }
        const int roff = l + 1;
#pragma unroll
        for (int q = 0; q < 8; ++q) {
            const int t  = (q + roff) & 7;
            const int bc = 7 - q;
            const int bt = 7 - t;
            if (bt >= 2) {
                const int xm = 1 << (bt - 2);
                if (bc >= 2) {
                    const int cbit = (lane >> (bc - 2)) & 1;
#pragma unroll
                    for (int r = 0; r < 4; ++r) {
                        const float oR = __shfl_xor(ar[r], xm, 64);
                        const float oI = __shfl_xor(ai[r], xm, 64);
                        ar[r] = cbit ? oR : ar[r];
                        ai[r] = cbit ? oI : ai[r];
                    }
                } else {
#pragma unroll
                    for (int r = 0; r < 4; ++r) {
                        if ((r >> bc) & 1) {
                            ar[r] = __shfl_xor(ar[r], xm, 64);
                            ai[r] = __shfl_xor(ai[r], xm, 64);
                        }
                    }
                }
            } else {
                const int step = 1 << bt;
                if (bc >= 2) {
                    const int cbit = (lane >> (bc - 2)) & 1;
#pragma unroll
                    for (int r0 = 0; r0 < 4; ++r0) {
                        if (((r0 >> bt) & 1) == 0) {
                            const int r1 = r0 | step;
                            const float t0r = cbit ? ar[r1] : ar[r0];
                            const float t0i = cbit ? ai[r1] : ai[r0];
                            const float t1r = cbit ? ar[r0] : ar[r1];
                            const float t1i = cbit ? ai[r0] : ai[r1];
                            ar[r0] = t0r; ai[r0] = t0i;
                            ar[r1] = t1r; ai[r1] = t1i;
                        }
                    }
                } else {
#pragma unroll
                    for (int r0 = 0; r0 < 4; ++r0) {
                        if (((r0 >> bc) & 1) == 1 && ((r0 >> bt) & 1) == 0) {
                            const int r1 = r0 | step;
                            float tr = ar[r0]; ar[r0] = ar[r1]; ar[r1] = tr;
                            float ti = ai[r0]; ai[r0] = ai[r1]; ai[r1] = ti;
                        }
                    }
                }
            }
        }
    }

    // store column j of U_v as bf16, row-major [i][j] (i contiguous-major rows)
    ushort* ur = Ure + v * 65536;
    ushort* ui = Uim + v * 65536;
#pragma unroll
    for (int r = 0; r < 4; ++r) {
        const int i = lane * 4 + r;
        ur[i * 256 + j] = f2bf(ar[r]);
        ui[i * 256 + j] = f2bf(ai[r]);
    }
}

// ---------------- fused main kernel ---------------------------------------
// 256 blocks x 512 threads; block owns 128 batch rows through all 4 VQCs.
// Wave w: cg = w&3 (64-col group), rg = w>>2 (64-row group).
__global__ __launch_bounds__(512, 2)
void vqc_mfma_k(const float* __restrict__ xg,
                const ushort* __restrict__ Ure, const ushort* __restrict__ Uim,
                float* __restrict__ out) {
    __shared__ ushort s_lds[128 * 256];       // 64 KB, XOR-swizzled bf16
    __shared__ float  ex_part[4][128][8];     // 16 KB
    __shared__ float  x_lds[128][8];          // 4 KB

    const int tid  = threadIdx.x;
    const int lane = tid & 63;
    const int w    = tid >> 6;
    const int cg   = w & 3;
    const int rg   = w >> 2;
    const int l15  = lane & 15;
    const int g4   = lane >> 4;
    const int rowbase = blockIdx.x * 128;

    // butterfly signs for lane bits 0..3
    const float sg0 = (lane & 1) ? -1.f : 1.f;
    const float sg1 = (lane & 2) ? -1.f : 1.f;
    const float sg2 = (lane & 4) ? -1.f : 1.f;
    const float sg3 = (lane & 8) ? -1.f : 1.f;

    // initial x into LDS (1024 floats)
    ((float2*)x_lds)[tid] = ((const float2*)(xg + (size_t)rowbase * 8))[tid];
    __syncthreads();

    const int srow = tid >> 2;     // s-build: 4 threads per row
    const int sc   = tid & 3;      // 64-amp chunk (amp bits 7,6)

    for (int v = 0; v < 4; ++v) {
        // ---- (a) build s[row][k] = prod_b f_b(k_b), bf16 swizzled ----
        {
            float hc[8], hs[8];
#pragma unroll
            for (int q = 0; q < 8; ++q) {
                float h = 0.5f * x_lds[srow][q];
                hs[q] = __sinf(h); hc[q] = __cosf(h);
            }
            // amp bit7 <-> qubit 0, bit6 <-> qubit 1 (chunk bits)
            float arr[64];
            arr[0] = ((sc >> 1) ? hs[0] : hc[0]) * ((sc & 1) ? hs[1] : hc[1]);
#define LVL(LEN, FC, FS)                                            \
            _Pragma("unroll")                                       \
            for (int m = (LEN) - 1; m >= 0; --m) {                  \
                arr[2*m+1] = arr[m] * (FS);                         \
                arr[2*m]   = arr[m] * (FC);                         \
            }
            LVL(1,  hc[2], hs[2])   // bit5
            LVL(2,  hc[3], hs[3])   // bit4
            LVL(4,  hc[4], hs[4])   // bit3
            LVL(8,  hc[5], hs[5])   // bit2
            LVL(16, hc[6], hs[6])   // bit1
            LVL(32, hc[7], hs[7])   // bit0
#undef LVL
            char* sb = (char*)s_lds + srow * 512;
            const int swz = (srow & 7) << 4;
#pragma unroll
            for (int j = 0; j < 8; ++j) {
                uint4 wv;
                wv.x = pack2(arr[j*8+0], arr[j*8+1]);
                wv.y = pack2(arr[j*8+2], arr[j*8+3]);
                wv.z = pack2(arr[j*8+4], arr[j*8+5]);
                wv.w = pack2(arr[j*8+6], arr[j*8+7]);
                *(uint4*)(sb + ((sc * 128 + j * 16) ^ swz)) = wv;
            }
        }
        __syncthreads();

        // ---- (b) GEMM: Y(re,im)[64r x 64c per wave] = s @ U^T ----
        const ushort* Ur = Ure + v * 65536;
        const ushort* Ui = Uim + v * 65536;
        f32x4 accr[4][4], acci[4][4];
#pragma unroll
        for (int rb = 0; rb < 4; ++rb)
#pragma unroll
            for (int cb = 0; cb < 4; ++cb) {
                accr[rb][cb] = (f32x4){0.f, 0.f, 0.f, 0.f};
                acci[rb][cb] = (f32x4){0.f, 0.f, 0.f, 0.f};
            }

#pragma unroll
        for (int ks = 0; ks < 8; ++ks) {
            bf16x8 afr[4];
#pragma unroll
            for (int rb = 0; rb < 4; ++rb) {
                const int row = rg * 64 + rb * 16 + l15;
                const int off = row * 512 + (((ks * 64) + (g4 << 4)) ^ ((row & 7) << 4));
                afr[rb] = *(const bf16x8*)((const char*)s_lds + off);
            }
#pragma unroll
            for (int cb = 0; cb < 4; ++cb) {
                const int col = cg * 64 + cb * 16 + l15;
                const int off = col * 256 + ks * 32 + (g4 << 3);
                const bf16x8 bfr = *(const bf16x8*)(Ur + off);
                const bf16x8 bfi = *(const bf16x8*)(Ui + off);
#pragma unroll
                for (int rb = 0; rb < 4; ++rb) {
                    accr[rb][cb] = __builtin_amdgcn_mfma_f32_16x16x32_bf16(
                        afr[rb], bfr, accr[rb][cb], 0, 0, 0);
                    acci[rb][cb] = __builtin_amdgcn_mfma_f32_16x16x32_bf16(
                        afr[rb], bfi, acci[rb][cb], 0, 0, 0);
                }
            }
        }

        // ---- (c) p = |Y|^2; per-slot WHT over cb + carried signed butterfly
        // col bits: [3:0]=lane&15, [5:4]=cb, [7:6]=cg. qubit q <-> col bit 7-q.
#pragma unroll
        for (int rb = 0; rb < 4; ++rb) {
#pragma unroll
            for (int r = 0; r < 4; ++r) {
                const float p0 = accr[rb][0][r]*accr[rb][0][r] + acci[rb][0][r]*acci[rb][0][r];
                const float p1 = accr[rb][1][r]*accr[rb][1][r] + acci[rb][1][r]*acci[rb][1][r];
                const float p2 = accr[rb][2][r]*accr[rb][2][r] + acci[rb][2][r]*acci[rb][2][r];
                const float p3 = accr[rb][3][r]*accr[rb][3][r] + acci[rb][3][r]*acci[rb][3][r];
                const float u  = p0 + p1, vv = p0 - p1;
                const float ww = p2 + p3, zz = p2 - p3;
                float T00 = u + ww;      // unsigned over cb  (q0,q1 after cg sign)
                float T10 = u - ww;      // signed cb bit1 -> col bit5 -> q2
                float T01 = vv + zz;     // signed cb bit0 -> col bit4 -> q3
                float d0, d1, d2, d3, pt;
                // step0 (mask1, col bit0 -> q7)
                pt = __shfl_xor(T00, 1, 64); d0 = sg0 * (T00 - pt); T00 += pt;
                pt = __shfl_xor(T01, 1, 64); T01 += pt;
                pt = __shfl_xor(T10, 1, 64); T10 += pt;
                // step1 (mask2 -> q6)
                pt = __shfl_xor(T00, 2, 64); d1 = sg1 * (T00 - pt); T00 += pt;
                pt = __shfl_xor(T01, 2, 64); T01 += pt;
                pt = __shfl_xor(T10, 2, 64); T10 += pt;
                pt = __shfl_xor(d0,  2, 64); d0  += pt;
                // step2 (mask4 -> q5)
                pt = __shfl_xor(T00, 4, 64); d2 = sg2 * (T00 - pt); T00 += pt;
                pt = __shfl_xor(T01, 4, 64); T01 += pt;
                pt = __shfl_xor(T10, 4, 64); T10 += pt;
                pt = __shfl_xor(d0,  4, 64); d0  += pt;
                pt = __shfl_xor(d1,  4, 64); d1  += pt;
                // step3 (mask8 -> q4)
                pt = __shfl_xor(T00, 8, 64); d3 = sg3 * (T00 - pt); T00 += pt;
                pt = __shfl_xor(T01, 8, 64); T01 += pt;
                pt = __shfl_xor(T10, 8, 64); T10 += pt;
                pt = __shfl_xor(d0,  8, 64); d0  += pt;
                pt = __shfl_xor(d1,  8, 64); d1  += pt;
                pt = __shfl_xor(d2,  8, 64); d2  += pt;
                if (l15 == 0) {
                    const int row = rg * 64 + rb * 16 + g4 * 4 + r;
                    float* e = &ex_part[cg][row][0];
                    e[0] = T00; e[1] = T00; e[2] = T10; e[3] = T01;
                    e[4] = d3;  e[5] = d2;  e[6] = d1;  e[7] = d0;
                }
            }
        }
        __syncthreads();

        // ---- (d) combine col-groups: q0 sign by cg bit1, q1 by cg bit0 ----
#pragma unroll
        for (int u0 = 0; u0 < 2; ++u0) {
            const int idx = tid + u0 * 512;     // 0..1023
            const int row = idx >> 3, q = idx & 7;
            const float e0 = ex_part[0][row][q], e1 = ex_part[1][row][q];
            const float e2 = ex_part[2][row][q], e3 = ex_part[3][row][q];
            float val;
            if (q == 0)      val = (e0 + e1) - (e2 + e3);
            else if (q == 1) val = (e0 - e1) + (e2 - e3);
            else             val = (e0 + e1) + (e2 + e3);
            x_lds[row][q] = val;
        }
        __syncthreads();
    }

    // output = H[:,4] * float(pi - eps_f32)
    const float MULT = 3.14159253589793f;   // float(np.float64(pi) - 1.1920929e-7)
    if (tid < 128) out[rowbase + tid] = x_lds[tid][4] * MULT;
}

// ---------------- launcher ------------------------------------------------
extern "C" void kernel_launch(void* const* d_in, const int* in_sizes, int n_in,
                              void* d_out, int out_size, void* d_ws, size_t ws_size,
                              hipStream_t stream) {
    const float* x     = (const float*)d_in[0];   // (32768, 8) fp32
    const float* theta = (const float*)d_in[1];   // (4, 4, 8, 3) fp32
    float* out = (float*)d_out;                   // (32768,) fp32

    char*   ws  = (char*)d_ws;
    float*  gt  = (float*)ws;                         // 4 KB
    ushort* Ure = (ushort*)(ws + 4096);               // 512 KB
    ushort* Uim = (ushort*)(ws + 4096 + 524288);      // 512 KB

    gate_table_k<<<1, 128, 0, stream>>>(theta, gt);
    ubuild_k<<<256, 256, 0, stream>>>(gt, Ure, Uim);
    vqc_mfma_k<<<256, 512, 0, stream>>>(x, Ure, Uim, out);
}

// Round 4
// 204.839 us; speedup vs baseline: 2.9215x; 1.0037x over previous
//
#include <hip/hip_runtime.h>

// SingleVQC via MFMA: each VQC block = RY(x) state build (real tensor product)
// followed by a FIXED 256x256 complex unitary U_v (depends only on theta) and
// Z-expvals. U_v is prebuilt (bf16) by simulating 256 basis columns with the
// verified shuffle-sim machinery; the main kernel does fused
// s-build -> bf16 GEMM (re,im) -> |Y|^2 -> signed reductions -> sin/cos, x4 VQCs.
//
// Amplitude bit convention (from reference reshape): qubit q <-> amp bit 7-q.
// R4 changes vs R3 (spill fix): __launch_bounds__(512,1) lifts the VGPR cap
// 128->256 (acc alone is 128; R3 spilled ~50 MB/dispatch to scratch);
// ex_part padded [8]->[9] to break the stride-8 bank pattern.

typedef __attribute__((ext_vector_type(8))) short  bf16x8;
typedef __attribute__((ext_vector_type(4))) float  f32x4;

__device__ __forceinline__ ushort f2bf(float f) {
    unsigned u = __builtin_bit_cast(unsigned, f);
    u += 0x7fffu + ((u >> 16) & 1u);          // RNE
    return (ushort)(u >> 16);
}
__device__ __forceinline__ unsigned pack2(float a, float b) {
    return ((unsigned)f2bf(b) << 16) | (unsigned)f2bf(a);
}

// ---------------- gate-table prologue (unchanged, verified) ---------------
__global__ void gate_table_k(const float* __restrict__ theta,
                             float* __restrict__ gt) {
    int idx = blockIdx.x * blockDim.x + threadIdx.x;
    if (idx >= 128) return;
    float phi = theta[idx * 3 + 0];
    float th  = theta[idx * 3 + 1];
    float om  = theta[idx * 3 + 2];
    float ct = __cosf(0.5f * th),         st = __sinf(0.5f * th);
    float ca = __cosf(0.5f * (phi - om)), sa = __sinf(0.5f * (phi - om));
    float cb = __cosf(0.5f * (phi + om)), sb = __sinf(0.5f * (phi + om));
    float* g = gt + idx * 8;
    g[0] =  cb * ct;  g[1] = -sb * ct;
    g[2] = -ca * st;  g[3] = -sa * st;
    g[4] =  ca * st;  g[5] = -sa * st;
    g[6] =  cb * ct;  g[7] =  sb * ct;
}

// ---------------- U-build: one wave per (vqc, basis column) ---------------
__global__ void ubuild_k(const float* __restrict__ gt,
                         ushort* __restrict__ Ure, ushort* __restrict__ Uim) {
    const int lane = threadIdx.x & 63;
    const int wid  = threadIdx.x >> 6;
    const int wg   = blockIdx.x * 4 + wid;     // 0..1023
    const int v    = wg >> 8;                  // 0..3
    const int j    = wg & 255;                 // basis column

    float ar[4], ai[4];
#pragma unroll
    for (int r = 0; r < 4; ++r) {
        ar[r] = ((lane * 4 + r) == j) ? 1.0f : 0.0f;
        ai[r] = 0.0f;
    }

#pragma unroll
    for (int l = 0; l < 4; ++l) {
        const float* gl = gt + ((v * 4 + l) * 8) * 8;
#pragma unroll
        for (int q = 0; q < 8; ++q) {
            const float* g = gl + q * 8;
            const float g00r = g[0], g00i = g[1], g01r = g[2], g01i = g[3];
            const float g10r = g[4], g10i = g[5], g11r = g[6], g11i = g[7];
            const int b = 7 - q;
            if (b >= 2) {
                const int xm    = 1 << (b - 2);
                const int mybit = (lane >> (b - 2)) & 1;
                const float cAr = mybit ? g11r : g00r;
                const float cAi = mybit ? g11i : g00i;
                const float cBr = mybit ? g10r : g01r;
                const float cBi = mybit ? g10i : g01i;
#pragma unroll
                for (int r = 0; r < 4; ++r) {
                    const float oR = __shfl_xor(ar[r], xm, 64);
                    const float oI = __shfl_xor(ai[r], xm, 64);
                    const float nR = cAr * ar[r] - cAi * ai[r] + cBr * oR - cBi * oI;
                    const float nI = cAr * ai[r] + cAi * ar[r] + cBr * oI + cBi * oR;
                    ar[r] = nR; ai[r] = nI;
                }
            } else {
                const int step = 1 << b;
#pragma unroll
                for (int r0 = 0; r0 < 4; ++r0) {
                    if ((r0 & step) == 0) {
                        const int r1 = r0 | step;
                        const float a0r = ar[r0], a0i = ai[r0];
                        const float a1r = ar[r1], a1i = ai[r1];
                        ar[r0] = g00r * a0r - g00i * a0i + g01r * a1r - g01i * a1i;
                        ai[r0] = g00r * a0i + g00i * a0r + g01r * a1i + g01i * a1r;
                        ar[r1] = g10r * a0r - g10i * a0i + g11r * a1r - g11i * a1i;
                        ai[r1] = g10r * a0i + g10i * a0r + g11r * a1i + g11i * a1r;
                    }
                }
            }
        }
        const int roff = l + 1;
#pragma unroll
        for (int q = 0; q < 8; ++q) {
            const int t  = (q + roff) & 7;
            const int bc = 7 - q;
            const int bt = 7 - t;
            if (bt >= 2) {
                const int xm = 1 << (bt - 2);
                if (bc >= 2) {
                    const int cbit = (lane >> (bc - 2)) & 1;
#pragma unroll
                    for (int r = 0; r < 4; ++r) {
                        const float oR = __shfl_xor(ar[r], xm, 64);
                        const float oI = __shfl_xor(ai[r], xm, 64);
                        ar[r] = cbit ? oR : ar[r];
                        ai[r] = cbit ? oI : ai[r];
                    }
                } else {
#pragma unroll
                    for (int r = 0; r < 4; ++r) {
                        if ((r >> bc) & 1) {
                            ar[r] = __shfl_xor(ar[r], xm, 64);
                            ai[r] = __shfl_xor(ai[r], xm, 64);
                        }
                    }
                }
            } else {
                const int step = 1 << bt;
                if (bc >= 2) {
                    const int cbit = (lane >> (bc - 2)) & 1;
#pragma unroll
                    for (int r0 = 0; r0 < 4; ++r0) {
                        if (((r0 >> bt) & 1) == 0) {
                            const int r1 = r0 | step;
                            const float t0r = cbit ? ar[r1] : ar[r0];
                            const float t0i = cbit ? ai[r1] : ai[r0];
                            const float t1r = cbit ? ar[r0] : ar[r1];
                            const float t1i = cbit ? ai[r0] : ai[r1];
                            ar[r0] = t0r; ai[r0] = t0i;
                            ar[r1] = t1r; ai[r1] = t1i;
                        }
                    }
                } else {
#pragma unroll
                    for (int r0 = 0; r0 < 4; ++r0) {
                        if (((r0 >> bc) & 1) == 1 && ((r0 >> bt) & 1) == 0) {
                            const int r1 = r0 | step;
                            float tr = ar[r0]; ar[r0] = ar[r1]; ar[r1] = tr;
                            float ti = ai[r0]; ai[r0] = ai[r1]; ai[r1] = ti;
                        }
                    }
                }
            }
        }
    }

    // store column j of U_v as bf16, row-major [i][j]
    ushort* ur = Ure + v * 65536;
    ushort* ui = Uim + v * 65536;
#pragma unroll
    for (int r = 0; r < 4; ++r) {
        const int i = lane * 4 + r;
        ur[i * 256 + j] = f2bf(ar[r]);
        ui[i * 256 + j] = f2bf(ai[r]);
    }
}

// ---------------- fused main kernel ---------------------------------------
// 256 blocks x 512 threads; block owns 128 batch rows through all 4 VQCs.
// Wave w: cg = w&3 (64-col group), rg = w>>2 (64-row group).
__global__ __launch_bounds__(512, 1)
void vqc_mfma_k(const float* __restrict__ xg,
                const ushort* __restrict__ Ure, const ushort* __restrict__ Uim,
                float* __restrict__ out) {
    __shared__ ushort s_lds[128 * 256];       // 64 KB, XOR-swizzled bf16
    __shared__ float  ex_part[4][128][9];     // 18 KB (pad 9 breaks bank stride)
    __shared__ float  x_lds[128][8];          // 4 KB

    const int tid  = threadIdx.x;
    const int lane = tid & 63;
    const int w    = tid >> 6;
    const int cg   = w & 3;
    const int rg   = w >> 2;
    const int l15  = lane & 15;
    const int g4   = lane >> 4;
    const int rowbase = blockIdx.x * 128;

    // butterfly signs for lane bits 0..3
    const float sg0 = (lane & 1) ? -1.f : 1.f;
    const float sg1 = (lane & 2) ? -1.f : 1.f;
    const float sg2 = (lane & 4) ? -1.f : 1.f;
    const float sg3 = (lane & 8) ? -1.f : 1.f;

    // initial x into LDS (1024 floats)
    ((float2*)x_lds)[tid] = ((const float2*)(xg + (size_t)rowbase * 8))[tid];
    __syncthreads();

    const int srow = tid >> 2;     // s-build: 4 threads per row
    const int sc   = tid & 3;      // 64-amp chunk (amp bits 7,6)

    for (int v = 0; v < 4; ++v) {
        // ---- (a) build s[row][k] = prod_b f_b(k_b), bf16 swizzled ----
        {
            float hc[8], hs[8];
#pragma unroll
            for (int q = 0; q < 8; ++q) {
                float h = 0.5f * x_lds[srow][q];
                hs[q] = __sinf(h); hc[q] = __cosf(h);
            }
            // amp bit7 <-> qubit 0, bit6 <-> qubit 1 (chunk bits)
            float arr[64];
            arr[0] = ((sc >> 1) ? hs[0] : hc[0]) * ((sc & 1) ? hs[1] : hc[1]);
#define LVL(LEN, FC, FS)                                            \
            _Pragma("unroll")                                       \
            for (int m = (LEN) - 1; m >= 0; --m) {                  \
                arr[2*m+1] = arr[m] * (FS);                         \
                arr[2*m]   = arr[m] * (FC);                         \
            }
            LVL(1,  hc[2], hs[2])   // bit5
            LVL(2,  hc[3], hs[3])   // bit4
            LVL(4,  hc[4], hs[4])   // bit3
            LVL(8,  hc[5], hs[5])   // bit2
            LVL(16, hc[6], hs[6])   // bit1
            LVL(32, hc[7], hs[7])   // bit0
#undef LVL
            char* sb = (char*)s_lds + srow * 512;
            const int swz = (srow & 7) << 4;
#pragma unroll
            for (int j = 0; j < 8; ++j) {
                uint4 wv;
                wv.x = pack2(arr[j*8+0], arr[j*8+1]);
                wv.y = pack2(arr[j*8+2], arr[j*8+3]);
                wv.z = pack2(arr[j*8+4], arr[j*8+5]);
                wv.w = pack2(arr[j*8+6], arr[j*8+7]);
                *(uint4*)(sb + ((sc * 128 + j * 16) ^ swz)) = wv;
            }
        }
        __syncthreads();

        // ---- (b) GEMM: Y(re,im)[64r x 64c per wave] = s @ U^T ----
        const ushort* Ur = Ure + v * 65536;
        const ushort* Ui = Uim + v * 65536;
        f32x4 accr[4][4], acci[4][4];
#pragma unroll
        for (int rb = 0; rb < 4; ++rb)
#pragma unroll
            for (int cb = 0; cb < 4; ++cb) {
                accr[rb][cb] = (f32x4){0.f, 0.f, 0.f, 0.f};
                acci[rb][cb] = (f32x4){0.f, 0.f, 0.f, 0.f};
            }

#pragma unroll
        for (int ks = 0; ks < 8; ++ks) {
            bf16x8 afr[4];
#pragma unroll
            for (int rb = 0; rb < 4; ++rb) {
                const int row = rg * 64 + rb * 16 + l15;
                const int off = row * 512 + (((ks * 64) + (g4 << 4)) ^ ((row & 7) << 4));
                afr[rb] = *(const bf16x8*)((const char*)s_lds + off);
            }
#pragma unroll
            for (int cb = 0; cb < 4; ++cb) {
                const int col = cg * 64 + cb * 16 + l15;
                const int off = col * 256 + ks * 32 + (g4 << 3);
                const bf16x8 bfr = *(const bf16x8*)(Ur + off);
                const bf16x8 bfi = *(const bf16x8*)(Ui + off);
#pragma unroll
                for (int rb = 0; rb < 4; ++rb) {
                    accr[rb][cb] = __builtin_amdgcn_mfma_f32_16x16x32_bf16(
                        afr[rb], bfr, accr[rb][cb], 0, 0, 0);
                    acci[rb][cb] = __builtin_amdgcn_mfma_f32_16x16x32_bf16(
                        afr[rb], bfi, acci[rb][cb], 0, 0, 0);
                }
            }
        }

        // ---- (c) p = |Y|^2; per-slot WHT over cb + carried signed butterfly
        // col bits: [3:0]=lane&15, [5:4]=cb, [7:6]=cg. qubit q <-> col bit 7-q.
#pragma unroll
        for (int rb = 0; rb < 4; ++rb) {
#pragma unroll
            for (int r = 0; r < 4; ++r) {
                const float p0 = accr[rb][0][r]*accr[rb][0][r] + acci[rb][0][r]*acci[rb][0][r];
                const float p1 = accr[rb][1][r]*accr[rb][1][r] + acci[rb][1][r]*acci[rb][1][r];
                const float p2 = accr[rb][2][r]*accr[rb][2][r] + acci[rb][2][r]*acci[rb][2][r];
                const float p3 = accr[rb][3][r]*accr[rb][3][r] + acci[rb][3][r]*acci[rb][3][r];
                const float u  = p0 + p1, vv = p0 - p1;
                const float ww = p2 + p3, zz = p2 - p3;
                float T00 = u + ww;      // unsigned over cb  (q0,q1 after cg sign)
                float T10 = u - ww;      // signed cb bit1 -> col bit5 -> q2
                float T01 = vv + zz;     // signed cb bit0 -> col bit4 -> q3
                float d0, d1, d2, d3, pt;
                // step0 (mask1, col bit0 -> q7)
                pt = __shfl_xor(T00, 1, 64); d0 = sg0 * (T00 - pt); T00 += pt;
                pt = __shfl_xor(T01, 1, 64); T01 += pt;
                pt = __shfl_xor(T10, 1, 64); T10 += pt;
                // step1 (mask2 -> q6)
                pt = __shfl_xor(T00, 2, 64); d1 = sg1 * (T00 - pt); T00 += pt;
                pt = __shfl_xor(T01, 2, 64); T01 += pt;
                pt = __shfl_xor(T10, 2, 64); T10 += pt;
                pt = __shfl_xor(d0,  2, 64); d0  += pt;
                // step2 (mask4 -> q5)
                pt = __shfl_xor(T00, 4, 64); d2 = sg2 * (T00 - pt); T00 += pt;
                pt = __shfl_xor(T01, 4, 64); T01 += pt;
                pt = __shfl_xor(T10, 4, 64); T10 += pt;
                pt = __shfl_xor(d0,  4, 64); d0  += pt;
                pt = __shfl_xor(d1,  4, 64); d1  += pt;
                // step3 (mask8 -> q4)
                pt = __shfl_xor(T00, 8, 64); d3 = sg3 * (T00 - pt); T00 += pt;
                pt = __shfl_xor(T01, 8, 64); T01 += pt;
                pt = __shfl_xor(T10, 8, 64); T10 += pt;
                pt = __shfl_xor(d0,  8, 64); d0  += pt;
                pt = __shfl_xor(d1,  8, 64); d1  += pt;
                pt = __shfl_xor(d2,  8, 64); d2  += pt;
                if (l15 == 0) {
                    const int row = rg * 64 + rb * 16 + g4 * 4 + r;
                    float* e = &ex_part[cg][row][0];
                    e[0] = T00; e[1] = T00; e[2] = T10; e[3] = T01;
                    e[4] = d3;  e[5] = d2;  e[6] = d1;  e[7] = d0;
                }
            }
        }
        __syncthreads();

        // ---- (d) combine col-groups: q0 sign by cg bit1, q1 by cg bit0 ----
#pragma unroll
        for (int u0 = 0; u0 < 2; ++u0) {
            const int idx = tid + u0 * 512;     // 0..1023
            const int row = idx >> 3, q = idx & 7;
            const float e0 = ex_part[0][row][q], e1 = ex_part[1][row][q];
            const float e2 = ex_part[2][row][q], e3 = ex_part[3][row][q];
            float val;
            if (q == 0)      val = (e0 + e1) - (e2 + e3);
            else if (q == 1) val = (e0 - e1) + (e2 - e3);
            else             val = (e0 + e1) + (e2 + e3);
            x_lds[row][q] = val;
        }
        __syncthreads();
    }

    // output = H[:,4] * float(pi - eps_f32)
    const float MULT = 3.14159253589793f;   // float(np.float64(pi) - eps_f32)
    if (tid < 128) out[rowbase + tid] = x_lds[tid][4] * MULT;
}

// ---------------- launcher ------------------------------------------------
extern "C" void kernel_launch(void* const* d_in, const int* in_sizes, int n_in,
                              void* d_out, int out_size, void* d_ws, size_t ws_size,
                              hipStream_t stream) {
    const float* x     = (const float*)d_in[0];   // (32768, 8) fp32
    const float* theta = (const float*)d_in[1];   // (4, 4, 8, 3) fp32
    float* out = (float*)d_out;                   // (32768,) fp32

    char*   ws  = (char*)d_ws;
    float*  gt  = (float*)ws;                         // 4 KB
    ushort* Ure = (ushort*)(ws + 4096);               // 512 KB
    ushort* Uim = (ushort*)(ws + 4096 + 524288);      // 512 KB

    gate_table_k<<<1, 128, 0, stream>>>(theta, gt);
    ubuild_k<<<256, 256, 0, stream>>>(gt, Ure, Uim);
    vqc_mfma_k<<<256, 512, 0, stream>>>(x, Ure, Uim, out);
}

// Round 5
// 188.570 us; speedup vs baseline: 3.1735x; 1.0863x over previous
//
#include <hip/hip_runtime.h>

// SingleVQC via MFMA: each VQC block = RY(x) state build (real tensor product)
// followed by a FIXED 256x256 complex unitary U_v (depends only on theta) and
// Z-expvals. U_v is prebuilt (bf16) by simulating 256 basis columns with the
// verified shuffle-sim machinery; the main kernel does fused
// s-build -> bf16 GEMM (re,im) -> |Y|^2 -> signed reductions -> sin/cos, x4 VQCs.
//
// Amplitude bit convention (from reference reshape): qubit q <-> amp bit 7-q.
// R5 changes vs R4 (kill scratch traffic, which was 156 MB/dispatch = the
// whole 143us): 64 rows/block (512 blocks), each wave does 32 cols x re+im
// -> acc 64 regs (was 128); s-build 8 threads/row -> arr[32] (was 64).
// Peak ~105 VGPR < 128 cap -> no spill.

typedef __attribute__((ext_vector_type(8))) short  bf16x8;
typedef __attribute__((ext_vector_type(4))) float  f32x4;

__device__ __forceinline__ ushort f2bf(float f) {
    unsigned u = __builtin_bit_cast(unsigned, f);
    u += 0x7fffu + ((u >> 16) & 1u);          // RNE
    return (ushort)(u >> 16);
}
__device__ __forceinline__ unsigned pack2(float a, float b) {
    return ((unsigned)f2bf(b) << 16) | (unsigned)f2bf(a);
}

// ---------------- gate-table prologue (unchanged, verified) ---------------
__global__ void gate_table_k(const float* __restrict__ theta,
                             float* __restrict__ gt) {
    int idx = blockIdx.x * blockDim.x + threadIdx.x;
    if (idx >= 128) return;
    float phi = theta[idx * 3 + 0];
    float th  = theta[idx * 3 + 1];
    float om  = theta[idx * 3 + 2];
    float ct = __cosf(0.5f * th),         st = __sinf(0.5f * th);
    float ca = __cosf(0.5f * (phi - om)), sa = __sinf(0.5f * (phi - om));
    float cb = __cosf(0.5f * (phi + om)), sb = __sinf(0.5f * (phi + om));
    float* g = gt + idx * 8;
    g[0] =  cb * ct;  g[1] = -sb * ct;
    g[2] = -ca * st;  g[3] = -sa * st;
    g[4] =  ca * st;  g[5] = -sa * st;
    g[6] =  cb * ct;  g[7] =  sb * ct;
}

// ---------------- U-build: one wave per (vqc, basis column) ---------------
__global__ void ubuild_k(const float* __restrict__ gt,
                         ushort* __restrict__ Ure, ushort* __restrict__ Uim) {
    const int lane = threadIdx.x & 63;
    const int wid  = threadIdx.x >> 6;
    const int wg   = blockIdx.x * 4 + wid;     // 0..1023
    const int v    = wg >> 8;                  // 0..3
    const int j    = wg & 255;                 // basis column

    float ar[4], ai[4];
#pragma unroll
    for (int r = 0; r < 4; ++r) {
        ar[r] = ((lane * 4 + r) == j) ? 1.0f : 0.0f;
        ai[r] = 0.0f;
    }

#pragma unroll
    for (int l = 0; l < 4; ++l) {
        const float* gl = gt + ((v * 4 + l) * 8) * 8;
#pragma unroll
        for (int q = 0; q < 8; ++q) {
            const float* g = gl + q * 8;
            const float g00r = g[0], g00i = g[1], g01r = g[2], g01i = g[3];
            const float g10r = g[4], g10i = g[5], g11r = g[6], g11i = g[7];
            const int b = 7 - q;
            if (b >= 2) {
                const int xm    = 1 << (b - 2);
                const int mybit = (lane >> (b - 2)) & 1;
                const float cAr = mybit ? g11r : g00r;
                const float cAi = mybit ? g11i : g00i;
                const float cBr = mybit ? g10r : g01r;
                const float cBi = mybit ? g10i : g01i;
#pragma unroll
                for (int r = 0; r < 4; ++r) {
                    const float oR = __shfl_xor(ar[r], xm, 64);
                    const float oI = __shfl_xor(ai[r], xm, 64);
                    const float nR = cAr * ar[r] - cAi * ai[r] + cBr * oR - cBi * oI;
                    const float nI = cAr * ai[r] + cAi * ar[r] + cBr * oI + cBi * oR;
                    ar[r] = nR; ai[r] = nI;
                }
            } else {
                const int step = 1 << b;
#pragma unroll
                for (int r0 = 0; r0 < 4; ++r0) {
                    if ((r0 & step) == 0) {
                        const int r1 = r0 | step;
                        const float a0r = ar[r0], a0i = ai[r0];
                        const float a1r = ar[r1], a1i = ai[r1];
                        ar[r0] = g00r * a0r - g00i * a0i + g01r * a1r - g01i * a1i;
                        ai[r0] = g00r * a0i + g00i * a0r + g01r * a1i + g01i * a1r;
                        ar[r1] = g10r * a0r - g10i * a0i + g11r * a1r - g11i * a1i;
                        ai[r1] = g10r * a0i + g10i * a0r + g11r * a1i + g11i * a1r;
                    }
                }
            }
        }
        const int roff = l + 1;
#pragma unroll
        for (int q = 0; q < 8; ++q) {
            const int t  = (q + roff) & 7;
            const int bc = 7 - q;
            const int bt = 7 - t;
            if (bt >= 2) {
                const int xm = 1 << (bt - 2);
                if (bc >= 2) {
                    const int cbit = (lane >> (bc - 2)) & 1;
#pragma unroll
                    for (int r = 0; r < 4; ++r) {
                        const float oR = __shfl_xor(ar[r], xm, 64);
                        const float oI = __shfl_xor(ai[r], xm, 64);
                        ar[r] = cbit ? oR : ar[r];
                        ai[r] = cbit ? oI : ai[r];
                    }
                } else {
#pragma unroll
                    for (int r = 0; r < 4; ++r) {
                        if ((r >> bc) & 1) {
                            ar[r] = __shfl_xor(ar[r], xm, 64);
                            ai[r] = __shfl_xor(ai[r], xm, 64);
                        }
                    }
                }
            } else {
                const int step = 1 << bt;
                if (bc >= 2) {
                    const int cbit = (lane >> (bc - 2)) & 1;
#pragma unroll
                    for (int r0 = 0; r0 < 4; ++r0) {
                        if (((r0 >> bt) & 1) == 0) {
                            const int r1 = r0 | step;
                            const float t0r = cbit ? ar[r1] : ar[r0];
                            const float t0i = cbit ? ai[r1] : ai[r0];
                            const float t1r = cbit ? ar[r0] : ar[r1];
                            const float t1i = cbit ? ai[r0] : ai[r1];
                            ar[r0] = t0r; ai[r0] = t0i;
                            ar[r1] = t1r; ai[r1] = t1i;
                        }
                    }
                } else {
#pragma unroll
                    for (int r0 = 0; r0 < 4; ++r0) {
                        if (((r0 >> bc) & 1) == 1 && ((r0 >> bt) & 1) == 0) {
                            const int r1 = r0 | step;
                            float tr = ar[r0]; ar[r0] = ar[r1]; ar[r1] = tr;
                            float ti = ai[r0]; ai[r0] = ai[r1]; ai[r1] = ti;
                        }
                    }
                }
            }
        }
    }

    // store column j of U_v as bf16, row-major [i][j]
    ushort* ur = Ure + v * 65536;
    ushort* ui = Uim + v * 65536;
#pragma unroll
    for (int r = 0; r < 4; ++r) {
        const int i = lane * 4 + r;
        ur[i * 256 + j] = f2bf(ar[r]);
        ui[i * 256 + j] = f2bf(ai[r]);
    }
}

// ---------------- fused main kernel ---------------------------------------
// 512 blocks x 512 threads; block owns 64 batch rows through all 4 VQCs.
// Wave w (0..7) owns 32 output cols (cols w*32..w*32+31), re AND im.
__global__ __launch_bounds__(512, 4)
void vqc_mfma_k(const float* __restrict__ xg,
                const ushort* __restrict__ Ure, const ushort* __restrict__ Uim,
                float* __restrict__ out) {
    __shared__ ushort s_lds[64 * 256];        // 32 KB, XOR-swizzled bf16
    __shared__ float  ex_part[8][64][9];      // 18 KB (pad 9 breaks stride-8)
    __shared__ float  x_lds[64][8];           // 2 KB

    const int tid  = threadIdx.x;
    const int lane = tid & 63;
    const int w    = tid >> 6;       // col group: cols w*32 .. w*32+31
    const int l15  = lane & 15;
    const int g4   = lane >> 4;
    const int rowbase = blockIdx.x * 64;

    // butterfly signs for lane bits 0..3
    const float sg0 = (lane & 1) ? -1.f : 1.f;
    const float sg1 = (lane & 2) ? -1.f : 1.f;
    const float sg2 = (lane & 4) ? -1.f : 1.f;
    const float sg3 = (lane & 8) ? -1.f : 1.f;

    // initial x into LDS (512 floats, one per thread)
    ((float*)x_lds)[tid] = xg[(size_t)rowbase * 8 + tid];
    __syncthreads();

    const int srow = tid >> 3;     // s-build: 8 threads per row
    const int sc   = tid & 7;      // 32-amp chunk (amp bits 7,6,5 = qubits 0,1,2)

    for (int v = 0; v < 4; ++v) {
        // ---- (a) build s[row][k] = prod_b f_b(k_b), bf16 swizzled ----
        {
            float hc[8], hs[8];
#pragma unroll
            for (int q = 0; q < 8; ++q) {
                float h = 0.5f * x_lds[srow][q];
                hs[q] = __sinf(h); hc[q] = __cosf(h);
            }
            float arr[32];
            arr[0] = (((sc >> 2) & 1) ? hs[0] : hc[0])
                   * (((sc >> 1) & 1) ? hs[1] : hc[1])
                   * (((sc     ) & 1) ? hs[2] : hc[2]);
#define LVL(LEN, FC, FS)                                            \
            _Pragma("unroll")                                       \
            for (int m = (LEN) - 1; m >= 0; --m) {                  \
                arr[2*m+1] = arr[m] * (FS);                         \
                arr[2*m]   = arr[m] * (FC);                         \
            }
            LVL(1,  hc[3], hs[3])   // amp bit4  (q3)
            LVL(2,  hc[4], hs[4])   // bit3      (q4)
            LVL(4,  hc[5], hs[5])   // bit2      (q5)
            LVL(8,  hc[6], hs[6])   // bit1      (q6)
            LVL(16, hc[7], hs[7])   // bit0      (q7)
#undef LVL
            char* sb = (char*)s_lds + srow * 512;
            const int swz = (srow & 7) << 4;
#pragma unroll
            for (int j = 0; j < 4; ++j) {
                uint4 wv;
                wv.x = pack2(arr[j*8+0], arr[j*8+1]);
                wv.y = pack2(arr[j*8+2], arr[j*8+3]);
                wv.z = pack2(arr[j*8+4], arr[j*8+5]);
                wv.w = pack2(arr[j*8+6], arr[j*8+7]);
                *(uint4*)(sb + ((sc * 64 + j * 16) ^ swz)) = wv;
            }
        }
        __syncthreads();

        // ---- (b) GEMM: per wave, Y(re,im)[64 rows x 32 cols] = s @ U^T ----
        const ushort* Ur = Ure + v * 65536;
        const ushort* Ui = Uim + v * 65536;
        f32x4 accr[4][2], acci[4][2];
#pragma unroll
        for (int rb = 0; rb < 4; ++rb)
#pragma unroll
            for (int cb = 0; cb < 2; ++cb) {
                accr[rb][cb] = (f32x4){0.f, 0.f, 0.f, 0.f};
                acci[rb][cb] = (f32x4){0.f, 0.f, 0.f, 0.f};
            }

#pragma unroll
        for (int ks = 0; ks < 8; ++ks) {
            bf16x8 afr[4];
#pragma unroll
            for (int rb = 0; rb < 4; ++rb) {
                const int row = rb * 16 + l15;
                const int off = row * 512 + (((ks * 64) + (g4 << 4)) ^ ((row & 7) << 4));
                afr[rb] = *(const bf16x8*)((const char*)s_lds + off);
            }
#pragma unroll
            for (int cb = 0; cb < 2; ++cb) {
                const int col = w * 32 + cb * 16 + l15;
                const int off = col * 256 + ks * 32 + (g4 << 3);
                const bf16x8 bfr = *(const bf16x8*)(Ur + off);
                const bf16x8 bfi = *(const bf16x8*)(Ui + off);
#pragma unroll
                for (int rb = 0; rb < 4; ++rb) {
                    accr[rb][cb] = __builtin_amdgcn_mfma_f32_16x16x32_bf16(
                        afr[rb], bfr, accr[rb][cb], 0, 0, 0);
                    acci[rb][cb] = __builtin_amdgcn_mfma_f32_16x16x32_bf16(
                        afr[rb], bfi, acci[rb][cb], 0, 0, 0);
                }
            }
        }

        // ---- (c) p = |Y|^2; in-thread cb combine + carried signed butterfly
        // col bits: [3:0]=l15, [4]=cb, [7:5]=w.  qubit q <-> col bit 7-q.
#pragma unroll
        for (int rb = 0; rb < 4; ++rb) {
#pragma unroll
            for (int r = 0; r < 4; ++r) {
                const float p0 = accr[rb][0][r]*accr[rb][0][r] + acci[rb][0][r]*acci[rb][0][r];
                const float p1 = accr[rb][1][r]*accr[rb][1][r] + acci[rb][1][r]*acci[rb][1][r];
                float T0 = p0 + p1;      // total (feeds q0..q2 via w-signs, and diffs)
                float T1 = p0 - p1;      // signed cb -> col bit4 -> q3
                float d0, d1, d2, d3, pt;
                // step0 (mask1, col bit0 -> q7)
                pt = __shfl_xor(T0, 1, 64); d0 = sg0 * (T0 - pt); T0 += pt;
                pt = __shfl_xor(T1, 1, 64); T1 += pt;
                // step1 (mask2 -> q6)
                pt = __shfl_xor(T0, 2, 64); d1 = sg1 * (T0 - pt); T0 += pt;
                pt = __shfl_xor(T1, 2, 64); T1 += pt;
                pt = __shfl_xor(d0, 2, 64); d0 += pt;
                // step2 (mask4 -> q5)
                pt = __shfl_xor(T0, 4, 64); d2 = sg2 * (T0 - pt); T0 += pt;
                pt = __shfl_xor(T1, 4, 64); T1 += pt;
                pt = __shfl_xor(d0, 4, 64); d0 += pt;
                pt = __shfl_xor(d1, 4, 64); d1 += pt;
                // step3 (mask8 -> q4)
                pt = __shfl_xor(T0, 8, 64); d3 = sg3 * (T0 - pt); T0 += pt;
                pt = __shfl_xor(T1, 8, 64); T1 += pt;
                pt = __shfl_xor(d0, 8, 64); d0 += pt;
                pt = __shfl_xor(d1, 8, 64); d1 += pt;
                pt = __shfl_xor(d2, 8, 64); d2 += pt;
                if (l15 == 0) {
                    const int row = rb * 16 + g4 * 4 + r;
                    float* e = &ex_part[w][row][0];
                    e[0] = T0; e[1] = T0; e[2] = T0; e[3] = T1;
                    e[4] = d3; e[5] = d2; e[6] = d1; e[7] = d0;
                }
            }
        }
        __syncthreads();

        // ---- (d) combine col-groups: q0 sign by w bit2, q1 by w bit1, q2 by w bit0
        {
            const int row = tid >> 3, q = tid & 7;
            const bool b2 = (q == 0), b1 = (q == 1), b0 = (q == 2);
            float acc = 0.f;
#pragma unroll
            for (int g = 0; g < 8; ++g) {
                const float e = ex_part[g][row][q];
                const bool neg = (b2 && (g & 4)) || (b1 && (g & 2)) || (b0 && (g & 1));
                acc += neg ? -e : e;
            }
            x_lds[row][q] = acc;
        }
        __syncthreads();
    }

    // output = H[:,4] * float(pi - eps_f32)
    const float MULT = 3.14159253589793f;
    if (tid < 64) out[rowbase + tid] = x_lds[tid][4] * MULT;
}

// ---------------- launcher ------------------------------------------------
extern "C" void kernel_launch(void* const* d_in, const int* in_sizes, int n_in,
                              void* d_out, int out_size, void* d_ws, size_t ws_size,
                              hipStream_t stream) {
    const float* x     = (const float*)d_in[0];   // (32768, 8) fp32
    const float* theta = (const float*)d_in[1];   // (4, 4, 8, 3) fp32
    float* out = (float*)d_out;                   // (32768,) fp32

    char*   ws  = (char*)d_ws;
    float*  gt  = (float*)ws;                         // 4 KB
    ushort* Ure = (ushort*)(ws + 4096);               // 512 KB
    ushort* Uim = (ushort*)(ws + 4096 + 524288);      // 512 KB

    gate_table_k<<<1, 128, 0, stream>>>(theta, gt);
    ubuild_k<<<256, 256, 0, stream>>>(gt, Ure, Uim);
    vqc_mfma_k<<<512, 512, 0, stream>>>(x, Ure, Uim, out);
}